// Round 2
// 680.353 us; speedup vs baseline: 1.0076x; 1.0076x over previous
//
#include <hip/hip_runtime.h>
#include <hip/hip_bf16.h>
#include <stdint.h>

#define T_TOK 8192
#define DDIM 1024
#define NEXP 8
#define IMOE 1024
#define ISH 4096
#define BK 64
#define PADTOT 17408  // 16384 pairs + 8*128 max padding (physical, 128-aligned)

typedef __attribute__((ext_vector_type(8))) short short8;
typedef __attribute__((ext_vector_type(8))) __bf16 bf16x8;
typedef __attribute__((ext_vector_type(4))) float floatx4;

// round-to-nearest-even fp32 -> bf16 bits
__device__ __forceinline__ unsigned short f2bf(float f) {
  union { float f; unsigned u; } v; v.f = f;
  unsigned r = v.u + 0x7fffu + ((v.u >> 16) & 1u);
  return (unsigned short)(r >> 16);
}

__device__ __forceinline__ floatx4 mfma16(short8 a, short8 b, floatx4 c) {
  return __builtin_amdgcn_mfma_f32_16x16x32_bf16(
      __builtin_bit_cast(bf16x8, a), __builtin_bit_cast(bf16x8, b), c, 0, 0, 0);
}

// async global->LDS, 16B per lane; LDS base must be wave-uniform (global addr IS per-lane)
__device__ __forceinline__ void gload16(const void* g, void* l) {
  __builtin_amdgcn_global_load_lds((const __attribute__((address_space(1))) void*)g,
                                   (__attribute__((address_space(3))) void*)l, 16, 0, 0);
}

// XOR swizzle: LDS 16B-block b of row r holds global block (b ^ (r&7)).
// Breaks the 16-way bank-group conflict of the BK=64 row stride (128B == 32 banks).

// ---------------- conversion kernels ----------------

__global__ void k_cast(const float* __restrict__ src, unsigned short* __restrict__ dst, int n) {
  int i = (blockIdx.x * blockDim.x + threadIdx.x) * 4;
  if (i < n) {
    float4 v = *(const float4*)(src + i);
    ushort4 o;
    o.x = f2bf(v.x); o.y = f2bf(v.y); o.z = f2bf(v.z); o.w = f2bf(v.w);
    *(ushort4*)(dst + i) = o;
  }
}

// src [batch][R][C] f32 -> dst [batch][C][R] bf16  (B^T layout for GEMM)
__global__ void k_transpose_cast(const float* __restrict__ src, unsigned short* __restrict__ dst,
                                 int R, int C) {
  __shared__ float tile[32][33];
  int b = blockIdx.z;
  int c0 = blockIdx.x * 32, r0 = blockIdx.y * 32;
  const float* s = src + (size_t)b * R * C;
  unsigned short* d = dst + (size_t)b * R * C;
  int tx = threadIdx.x, ty = threadIdx.y;  // 32 x 8
#pragma unroll
  for (int j = 0; j < 32; j += 8)
    tile[ty + j][tx] = s[(size_t)(r0 + ty + j) * C + c0 + tx];
  __syncthreads();
#pragma unroll
  for (int j = 0; j < 32; j += 8)
    d[(size_t)(c0 + ty + j) * R + r0 + tx] = f2bf(tile[tx][ty + j]);
}

// ---------------- router (no global atomics) ----------------

__global__ void k_router(const float* __restrict__ x, const float* __restrict__ gw,
                         const float* __restrict__ sgw, float* __restrict__ logits_out,
                         int* __restrict__ topi, float* __restrict__ topw,
                         float* __restrict__ sgate) {
  int wave = threadIdx.x >> 6;
  int lane = threadIdx.x & 63;
  int t = blockIdx.x * 4 + wave;
  const float* xr = x + (size_t)t * DDIM;
  float acc[9];
#pragma unroll
  for (int j = 0; j < 9; j++) acc[j] = 0.f;
  for (int d = lane; d < DDIM; d += 64) {
    float xv = xr[d];
    const float* g = gw + d * 8;
    float4 g0 = *(const float4*)g;
    float4 g1 = *(const float4*)(g + 4);
    acc[0] += xv * g0.x; acc[1] += xv * g0.y; acc[2] += xv * g0.z; acc[3] += xv * g0.w;
    acc[4] += xv * g1.x; acc[5] += xv * g1.y; acc[6] += xv * g1.z; acc[7] += xv * g1.w;
    acc[8] += xv * sgw[d];
  }
#pragma unroll
  for (int off = 32; off > 0; off >>= 1) {
#pragma unroll
    for (int j = 0; j < 9; j++) acc[j] += __shfl_xor(acc[j], off);
  }
  if (lane == 0) {
#pragma unroll
    for (int j = 0; j < 8; j++) logits_out[t * 8 + j] = acc[j];
    int i0 = 0;
#pragma unroll
    for (int j = 1; j < 8; j++) if (acc[j] > acc[i0]) i0 = j;
    int i1 = -1;
#pragma unroll
    for (int j = 0; j < 8; j++) {
      if (j == i0) continue;
      if (i1 < 0 || acc[j] > acc[i1]) i1 = j;
    }
    float e1 = expf(acc[i1] - acc[i0]);  // e0 = 1
    float inv = 1.f / (1.f + e1);
    topi[t * 2] = i0; topi[t * 2 + 1] = i1;
    topw[t * 2] = inv; topw[t * 2 + 1] = e1 * inv;
    sgate[t] = 1.f / (1.f + expf(-acc[8]));
  }
}

// Counting sort pass 1: per-block expert histogram (LDS atomics only).
__global__ void k_hist(const int* __restrict__ topi, int* __restrict__ blockhist) {
  __shared__ int h[NEXP];
  if (threadIdx.x < NEXP) h[threadIdx.x] = 0;
  __syncthreads();
  int i = blockIdx.x * 256 + threadIdx.x;  // pair index
  atomicAdd(&h[topi[i]], 1);
  __syncthreads();
  if (threadIdx.x < NEXP) blockhist[blockIdx.x * NEXP + threadIdx.x] = h[threadIdx.x];
}

// Pass 2: physical offsets (128-padded), virtual offsets (256-padded for BM=256 gu),
// per-block scatter bases, real counts.
__global__ void k_offsets(const int* __restrict__ blockhist, int* __restrict__ pseg,
                          int* __restrict__ rcnt, int* __restrict__ blockbase,
                          int* __restrict__ vseg) {
  if (threadIdx.x == 0) {
    int tot[NEXP];
#pragma unroll
    for (int e = 0; e < NEXP; e++) tot[e] = 0;
    for (int b = 0; b < 64; b++)
      for (int e = 0; e < NEXP; e++) {
        blockbase[b * NEXP + e] = tot[e];
        tot[e] += blockhist[b * NEXP + e];
      }
    int s = 0, vs = 0;
    for (int e = 0; e < NEXP; e++) {
      rcnt[e] = tot[e];
      pseg[e] = s;
      vseg[e] = vs;
      s += (tot[e] + 127) & ~127;   // physical pad to 128 (hp layout, down_expert BM)
      vs += (tot[e] + 255) & ~255;  // virtual pad to 256 (gu BM)
    }
    pseg[NEXP] = s;
    vseg[NEXP] = vs;
    for (int b = 0; b < 64; b++)
      for (int e = 0; e < NEXP; e++) blockbase[b * NEXP + e] += pseg[e];
  }
}

// Pass 3: scatter with per-block LDS cursors (no global atomics).
__global__ void k_scatter(const int* __restrict__ topi, const float* __restrict__ topw,
                          const int* __restrict__ blockbase,
                          int* __restrict__ ptok, float* __restrict__ pw) {
  __shared__ int cur[NEXP];
  if (threadIdx.x < NEXP) cur[threadIdx.x] = blockbase[blockIdx.x * NEXP + threadIdx.x];
  __syncthreads();
  int i = blockIdx.x * 256 + threadIdx.x;  // pair index
  int e = topi[i];
  int pos = atomicAdd(&cur[e], 1);
  ptok[pos] = i >> 1;
  pw[pos] = topw[i];
}

// ---------------- fused gate/up GEMM: 8-phase counted-vmcnt pipeline ----------------
// BM=256, BN=128 (dual B: gate+up), BK=64, 512 threads = 8 waves (2M x 4N).
// LDS 128 KiB full-tile double buffer. Per K-tile: 4 phases of 16 MFMA/wave;
// 2 global_load_lds issued per phase for the NEXT tile; counted s_waitcnt
// vmcnt(4)/vmcnt(2) at the two sync points -> load queue never drains.
// Issue order per tile: [A0,A2 | Bg0,Bg1 | Bu0,Bu1 | A1,A3]; vmcnt(2) at tile
// boundary lands {A0,A2,Bg*,Bu*} (consumed by phases 1-2); vmcnt(4) mid-tile
// lands {A1,A3} (consumed by phases 3-4).
// EXPERT variant: A rows are gathered on the fly from xb via per-lane ptok
// indirection (global side of global_load_lds is per-lane) over a virtual
// 256-padded row space mapped onto the physical 128-padded hp layout.

#define STG_A(NB, KK, P) gload16(ArowP[P] + (KK), &As[NB][((P)*64 + wave * 8) * BK])
#define STG_G(NB, KK, P) gload16(Bgrow + (size_t)(P) * 64 * DDIM + (KK), &Bgs[NB][((P)*64 + wave * 8) * BK])
#define STG_U(NB, KK, P) gload16(Burow + (size_t)(P) * 64 * DDIM + (KK), &Bus[NB][((P)*64 + wave * 8) * BK])

// One phase: 4 A-frag ds_reads, then gload issues, then 16 MFMA under setprio(1).
#define GU_PHASE(CB, MGI, MGOFF, SW, G0, G1, U0, U1, ...)                     \
  {                                                                           \
    const unsigned short* Abp = &As[CB][ab + (MGOFF) * BK + (SW)];            \
    short8 af0 = *(const short8*)(Abp);                                       \
    short8 af1 = *(const short8*)(Abp + 16 * BK);                             \
    short8 af2 = *(const short8*)(Abp + 32 * BK);                             \
    short8 af3 = *(const short8*)(Abp + 48 * BK);                             \
    __VA_ARGS__;                                                              \
    __builtin_amdgcn_s_setprio(1);                                            \
    accg[(MGI) + 0][0] = mfma16(af0, G0, accg[(MGI) + 0][0]);                 \
    accu[(MGI) + 0][0] = mfma16(af0, U0, accu[(MGI) + 0][0]);                 \
    accg[(MGI) + 0][1] = mfma16(af0, G1, accg[(MGI) + 0][1]);                 \
    accu[(MGI) + 0][1] = mfma16(af0, U1, accu[(MGI) + 0][1]);                 \
    accg[(MGI) + 1][0] = mfma16(af1, G0, accg[(MGI) + 1][0]);                 \
    accu[(MGI) + 1][0] = mfma16(af1, U0, accu[(MGI) + 1][0]);                 \
    accg[(MGI) + 1][1] = mfma16(af1, G1, accg[(MGI) + 1][1]);                 \
    accu[(MGI) + 1][1] = mfma16(af1, U1, accu[(MGI) + 1][1]);                 \
    accg[(MGI) + 2][0] = mfma16(af2, G0, accg[(MGI) + 2][0]);                 \
    accu[(MGI) + 2][0] = mfma16(af2, U0, accu[(MGI) + 2][0]);                 \
    accg[(MGI) + 2][1] = mfma16(af2, G1, accg[(MGI) + 2][1]);                 \
    accu[(MGI) + 2][1] = mfma16(af2, U1, accu[(MGI) + 2][1]);                 \
    accg[(MGI) + 3][0] = mfma16(af3, G0, accg[(MGI) + 3][0]);                 \
    accu[(MGI) + 3][0] = mfma16(af3, U0, accu[(MGI) + 3][0]);                 \
    accg[(MGI) + 3][1] = mfma16(af3, G1, accg[(MGI) + 3][1]);                 \
    accu[(MGI) + 3][1] = mfma16(af3, U1, accu[(MGI) + 3][1]);                 \
    __builtin_amdgcn_s_setprio(0);                                            \
  }

// One K-tile: compute from buffer CB, stage next tile (col base KK) into NB.
#define GU_TILE(CB, NB, KK)                                                         \
  {                                                                                 \
    const unsigned short* Bgb = &Bgs[CB][bb];                                       \
    const unsigned short* Bub = &Bus[CB][bb];                                       \
    short8 gA0 = *(const short8*)(Bgb + s0);                                        \
    short8 gA1 = *(const short8*)(Bgb + 16 * BK + s0);                              \
    short8 uA0 = *(const short8*)(Bub + s0);                                        \
    short8 uA1 = *(const short8*)(Bub + 16 * BK + s0);                              \
    GU_PHASE(CB, 0, 0, s0, gA0, gA1, uA0, uA1, STG_A(NB, KK, 0); STG_A(NB, KK, 2))  \
    __builtin_amdgcn_s_barrier();                                                   \
    short8 gB0 = *(const short8*)(Bgb + s1);                                        \
    short8 gB1 = *(const short8*)(Bgb + 16 * BK + s1);                              \
    short8 uB0 = *(const short8*)(Bub + s1);                                        \
    short8 uB1 = *(const short8*)(Bub + 16 * BK + s1);                              \
    GU_PHASE(CB, 0, 0, s1, gB0, gB1, uB0, uB1, STG_G(NB, KK, 0); STG_G(NB, KK, 1))  \
    asm volatile("s_waitcnt vmcnt(4)" ::: "memory");                                \
    __builtin_amdgcn_s_barrier();                                                   \
    __builtin_amdgcn_sched_barrier(0);                                              \
    GU_PHASE(CB, 4, 64, s0, gA0, gA1, uA0, uA1, STG_U(NB, KK, 0); STG_U(NB, KK, 1)) \
    __builtin_amdgcn_s_barrier();                                                   \
    GU_PHASE(CB, 4, 64, s1, gB0, gB1, uB0, uB1, STG_A(NB, KK, 1); STG_A(NB, KK, 3)) \
    asm volatile("s_waitcnt vmcnt(2)" ::: "memory");                                \
    __builtin_amdgcn_s_barrier();                                                   \
    __builtin_amdgcn_sched_barrier(0);                                              \
  }

template <int LDC, bool EXPERT>
__global__ __launch_bounds__(512) void k_gu8(
    const unsigned short* __restrict__ Ag,   // xb [8192][1024]
    const unsigned short* __restrict__ Bg0,  // [N][1024] (or [E][N][1024])
    const unsigned short* __restrict__ Bu0,
    const int* __restrict__ pseg,
    const int* __restrict__ vseg,
    const int* __restrict__ ptok,
    unsigned short* __restrict__ H)          // [M][LDC]
{
  const int m0 = blockIdx.x * 256;
  const unsigned short* Bg = Bg0;
  const unsigned short* Bu = Bu0;
  int pbase = 0, plen = 0, voff0 = m0;
  if constexpr (EXPERT) {
    if (m0 >= vseg[NEXP]) return;
    int e = 0;
#pragma unroll
    for (int j = 1; j < NEXP; j++) if (m0 >= vseg[j]) e = j;
    Bg = Bg0 + (size_t)e * IMOE * DDIM;
    Bu = Bu0 + (size_t)e * IMOE * DDIM;
    pbase = pseg[e];
    plen = pseg[e + 1] - pseg[e];   // physical (128-padded) segment length
    voff0 = m0 - vseg[e];           // virtual offset within segment
  }
  const int tn0 = blockIdx.y * 128;

  __shared__ __align__(16) unsigned short As[2][256 * BK];   // 64 KiB
  __shared__ __align__(16) unsigned short Bgs[2][128 * BK];  // 32 KiB
  __shared__ __align__(16) unsigned short Bus[2][128 * BK];  // 32 KiB

  const int tid = threadIdx.x;
  const int wave = tid >> 6, lane = tid & 63;
  const int wm = wave >> 2, wn = wave & 3;   // 2 M-halves x 4 N-quarters
  const int quad = lane >> 4, l16 = lane & 15;
  const int srow = lane >> 3;
  const int scol = ((lane & 7) ^ srow) * 8;  // pre-swizzled global col block

  // per-thread staging source rows (A: 4 parts of 64 rows; expert = ptok-indirect)
  const unsigned short* ArowP[4];
#pragma unroll
  for (int P = 0; P < 4; P++) {
    int vr = voff0 + P * 64 + wave * 8 + srow;
    int row;
    if constexpr (EXPERT) {
      int tok = (vr < plen) ? ptok[pbase + vr] : 0;
      if (tok < 0 || tok >= T_TOK) tok = 0;  // pad slots: ptok is garbage
      row = tok;
    } else {
      row = vr;  // voff0 == m0 for the shared path
    }
    ArowP[P] = Ag + (size_t)row * DDIM + scol;
  }
  const unsigned short* Bgrow = Bg + (size_t)(tn0 + wave * 8 + srow) * DDIM + scol;
  const unsigned short* Burow = Bu + (size_t)(tn0 + wave * 8 + srow) * DDIM + scol;

  // fragment read bases (fragment rows are l16 mod 16 -> swizzle folds to l16&7)
  const int ab = (wm * 128 + l16) * BK;
  const int bb = (wn * 32 + l16) * BK;
  const int s0 = ((quad) ^ (l16 & 7)) * 8;       // ks=0
  const int s1 = ((quad + 4) ^ (l16 & 7)) * 8;   // ks=32

  floatx4 accg[8][2] = {};
  floatx4 accu[8][2] = {};

  // prologue: stage tile 0 into buf0 in consumption order; keep A1,A3 in flight
  STG_A(0, 0, 0); STG_A(0, 0, 2);
  STG_G(0, 0, 0); STG_G(0, 0, 1);
  STG_U(0, 0, 0); STG_U(0, 0, 1);
  STG_A(0, 0, 1); STG_A(0, 0, 3);
  asm volatile("s_waitcnt vmcnt(2)" ::: "memory");
  __builtin_amdgcn_s_barrier();
  __builtin_amdgcn_sched_barrier(0);

#pragma unroll 1
  for (int k0 = 0; k0 < DDIM; k0 += 2 * BK) {
    const int kA = k0 + BK;
    const int kB = (k0 + 2 * BK < DDIM) ? (k0 + 2 * BK) : 0;  // wrap: dead prefetch on last iter
    GU_TILE(0, 1, kA)
    GU_TILE(1, 0, kB)
  }

#pragma unroll
  for (int fm = 0; fm < 8; fm++)
#pragma unroll
    for (int reg = 0; reg < 4; reg++) {
      int rr = voff0 + wm * 128 + fm * 16 + quad * 4 + reg;  // virtual row (or global for shared)
      bool ok = true;
      int r = rr;
      if constexpr (EXPERT) {
        ok = rr < plen;
        r = pbase + rr;
      }
      if (ok) {
#pragma unroll
        for (int fn = 0; fn < 2; fn++) {
          int c = tn0 + wn * 32 + fn * 16 + l16;
          float g = accg[fm][fn][reg];
          float u = accu[fm][fn][reg];
          H[(size_t)r * LDC + c] = f2bf((g / (1.f + __expf(-g))) * u);
        }
      }
    }
}

// ---------------- down-proj GEMM kernels (2-phase, unchanged) ----------------

// Shared-expert down proj: out = sigmoid_gate[t] * (Hsh @ sd). Writes full out.
__global__ __launch_bounds__(256, 4) void k_down_shared(
    const unsigned short* __restrict__ Hsh,  // [8192][4096]
    const unsigned short* __restrict__ SdT,  // [1024][4096]
    const float* __restrict__ sgate,
    float* __restrict__ out)                 // [8192][1024]
{
  __shared__ __align__(16) unsigned short As[128 * BK];
  __shared__ __align__(16) unsigned short Bs[128 * BK];

  const int tm0 = blockIdx.x * 128;
  const int tn0 = blockIdx.y * 128;
  const int tid = threadIdx.x;
  const int wave = tid >> 6, lane = tid & 63;
  const int wm = wave & 1, wn = wave >> 1;
  const int quad = lane >> 4, l16 = lane & 15;
  const int srow = lane >> 3;
  const int scol = ((lane & 7) ^ srow) * 8;

  floatx4 acc[4][4] = {};

  for (int k0 = 0; k0 < ISH; k0 += BK) {
#pragma unroll
    for (int s = 0; s < 4; s++) {
      int rb = (wave * 4 + s) * 8;
      gload16(Hsh + (size_t)(tm0 + rb + srow) * ISH + k0 + scol, As + rb * BK);
      gload16(SdT + (size_t)(tn0 + rb + srow) * ISH + k0 + scol, Bs + rb * BK);
    }
    __syncthreads();
#pragma unroll
    for (int ks = 0; ks < BK; ks += 32) {
      short8 af[4], bfr[4];
#pragma unroll
      for (int f = 0; f < 4; f++) {
        int ra = wm * 64 + f * 16 + l16;
        int rb2 = wn * 64 + f * 16 + l16;
        af[f] = *(const short8*)(As + ra * BK + ((((ks >> 3) + quad) ^ (ra & 7)) << 3));
        bfr[f] = *(const short8*)(Bs + rb2 * BK + ((((ks >> 3) + quad) ^ (rb2 & 7)) << 3));
      }
#pragma unroll
      for (int fm = 0; fm < 4; fm++)
#pragma unroll
        for (int fn = 0; fn < 4; fn++)
          acc[fm][fn] = mfma16(af[fm], bfr[fn], acc[fm][fn]);
    }
    __syncthreads();
  }
#pragma unroll
  for (int fm = 0; fm < 4; fm++)
#pragma unroll
    for (int reg = 0; reg < 4; reg++) {
      int r = tm0 + wm * 64 + fm * 16 + quad * 4 + reg;
      float gt = sgate[r];
#pragma unroll
      for (int fn = 0; fn < 4; fn++) {
        int c = tn0 + wn * 64 + fn * 16 + l16;
        out[(size_t)r * DDIM + c] = gt * acc[fm][fn][reg];
      }
    }
}

// Expert down proj: out[tok] += w_pair * (Hp @ ed[e]) via atomics. Sequential A.
__global__ __launch_bounds__(256, 4) void k_down_expert(
    const unsigned short* __restrict__ Hp,   // [PADTOT][1024]
    const unsigned short* __restrict__ EdT,  // [E][1024][1024]
    const int* __restrict__ pseg,
    const int* __restrict__ rcnt,
    const int* __restrict__ ptok,
    const float* __restrict__ pw,
    float* __restrict__ out)
{
  const int m0 = blockIdx.x * 128;
  if (m0 >= pseg[NEXP]) return;
  int e = 0;
#pragma unroll
  for (int j = 1; j < NEXP; j++) if (m0 >= pseg[j]) e = j;
  const int sbase = pseg[e];
  const int cnt = rcnt[e];

  __shared__ __align__(16) unsigned short As[128 * BK];
  __shared__ __align__(16) unsigned short Bs[128 * BK];

  const int tn0 = blockIdx.y * 128;
  const int tid = threadIdx.x;
  const int wave = tid >> 6, lane = tid & 63;
  const int wm = wave & 1, wn = wave >> 1;
  const int quad = lane >> 4, l16 = lane & 15;
  const int srow = lane >> 3;
  const int scol = ((lane & 7) ^ srow) * 8;

  const unsigned short* B = EdT + (size_t)e * IMOE * DDIM;

  floatx4 acc[4][4] = {};

  for (int k0 = 0; k0 < IMOE; k0 += BK) {
#pragma unroll
    for (int s = 0; s < 4; s++) {
      int rb = (wave * 4 + s) * 8;
      gload16(Hp + (size_t)(m0 + rb + srow) * IMOE + k0 + scol, As + rb * BK);
      gload16(B + (size_t)(tn0 + rb + srow) * IMOE + k0 + scol, Bs + rb * BK);
    }
    __syncthreads();
#pragma unroll
    for (int ks = 0; ks < BK; ks += 32) {
      short8 af[4], bfr[4];
#pragma unroll
      for (int f = 0; f < 4; f++) {
        int ra = wm * 64 + f * 16 + l16;
        int rb2 = wn * 64 + f * 16 + l16;
        af[f] = *(const short8*)(As + ra * BK + ((((ks >> 3) + quad) ^ (ra & 7)) << 3));
        bfr[f] = *(const short8*)(Bs + rb2 * BK + ((((ks >> 3) + quad) ^ (rb2 & 7)) << 3));
      }
#pragma unroll
      for (int fm = 0; fm < 4; fm++)
#pragma unroll
        for (int fn = 0; fn < 4; fn++)
          acc[fm][fn] = mfma16(af[fm], bfr[fn], acc[fm][fn]);
    }
    __syncthreads();
  }
#pragma unroll
  for (int fm = 0; fm < 4; fm++)
#pragma unroll
    for (int reg = 0; reg < 4; reg++) {
      int grow = m0 + wm * 64 + fm * 16 + quad * 4 + reg;
      if (grow - sbase < cnt) {
        int t = ptok[grow];
        float w = pw[grow];
#pragma unroll
        for (int fn = 0; fn < 4; fn++) {
          int c = tn0 + wn * 64 + fn * 16 + l16;
          atomicAdd(&out[(size_t)t * DDIM + c], w * acc[fm][fn][reg]);
        }
      }
    }
}

// ---------------- launch ----------------

extern "C" void kernel_launch(void* const* d_in, const int* in_sizes, int n_in,
                              void* d_out, int out_size, void* d_ws, size_t ws_size,
                              hipStream_t stream) {
  const float* x   = (const float*)d_in[0];
  const float* gw  = (const float*)d_in[1];
  const float* eg  = (const float*)d_in[2];
  const float* eu  = (const float*)d_in[3];
  const float* ed  = (const float*)d_in[4];
  const float* sg  = (const float*)d_in[5];
  const float* su  = (const float*)d_in[6];
  const float* sd  = (const float*)d_in[7];
  const float* sgw = (const float*)d_in[8];

  float* out    = (float*)d_out;                 // [8192][1024]
  float* logits = out + (size_t)T_TOK * DDIM;    // [8192][8]

  char* ws = (char*)d_ws;
  unsigned short* xb   = (unsigned short*)(ws + 0);            // 16 MB
  unsigned short* egT  = (unsigned short*)(ws + 16777216);     // 16 MB
  unsigned short* euT  = (unsigned short*)(ws + 33554432);     // 16 MB
  unsigned short* edT  = (unsigned short*)(ws + 50331648);     // 16 MB
  unsigned short* sgT  = (unsigned short*)(ws + 67108864);     // 8 MB
  unsigned short* suT  = (unsigned short*)(ws + 75497472);     // 8 MB
  unsigned short* sdT  = (unsigned short*)(ws + 83886080);     // 8 MB
  unsigned short* hsh  = (unsigned short*)(ws + 92274688);     // 64 MB
  unsigned short* hp   = (unsigned short*)(ws + 159383552);    // 35.65 MB (PADTOT rows)
  int*   topi      = (int*)  (ws + 195035136);   // 16384 ints
  float* topw      = (float*)(ws + 195100672);   // 16384 floats
  float* sgate     = (float*)(ws + 195166208);   // 8192 floats
  int*   ptok      = (int*)  (ws + 195198976);   // PADTOT ints
  float* pw        = (float*)(ws + 195268608);   // PADTOT floats
  int*   blockhist = (int*)  (ws + 195338240);   // 64*8 ints
  int*   blockbase = (int*)  (ws + 195340288);   // 64*8 ints
  int*   pseg      = (int*)  (ws + 195342336);   // 9 ints
  int*   rcnt      = (int*)  (ws + 195342400);   // 8 ints
  int*   vseg      = (int*)  (ws + 195342432);   // 9 ints

  k_cast<<<8192, 256, 0, stream>>>(x, xb, T_TOK * DDIM);
  k_transpose_cast<<<dim3(32, 32, 8), dim3(32, 8), 0, stream>>>(eg, egT, DDIM, IMOE);
  k_transpose_cast<<<dim3(32, 32, 8), dim3(32, 8), 0, stream>>>(eu, euT, DDIM, IMOE);
  k_transpose_cast<<<dim3(32, 32, 8), dim3(32, 8), 0, stream>>>(ed, edT, IMOE, DDIM);
  k_transpose_cast<<<dim3(128, 32, 1), dim3(32, 8), 0, stream>>>(sg, sgT, DDIM, ISH);
  k_transpose_cast<<<dim3(128, 32, 1), dim3(32, 8), 0, stream>>>(su, suT, DDIM, ISH);
  k_transpose_cast<<<dim3(32, 128, 1), dim3(32, 8), 0, stream>>>(sd, sdT, ISH, DDIM);

  k_router<<<T_TOK / 4, 256, 0, stream>>>(x, gw, sgw, logits, topi, topw, sgate);
  k_hist<<<64, 256, 0, stream>>>(topi, blockhist);
  k_offsets<<<1, 64, 0, stream>>>(blockhist, pseg, rcnt, blockbase, vseg);
  k_scatter<<<64, 256, 0, stream>>>(topi, topw, blockbase, ptok, pw);

  // virtual row space is at most 16384 + 8*255 padded -> 72 blocks of 256 cover it
  k_gu8<IMOE, true><<<dim3(72, IMOE / 128), 512, 0, stream>>>(xb, egT, euT, pseg, vseg, ptok, hp);
  k_gu8<ISH, false><<<dim3(T_TOK / 256, ISH / 128), 512, 0, stream>>>(xb, sgT, suT, nullptr, nullptr, nullptr, hsh);
  k_down_shared<<<dim3(64, 8), 256, 0, stream>>>(hsh, sdT, sgate, out);
  k_down_expert<<<dim3(PADTOT / 128, 8), 256, 0, stream>>>(hp, edT, pseg, rcnt, ptok, pw, out);

  (void)in_sizes; (void)n_in; (void)out_size; (void)ws_size;
}

// Round 4
// 647.930 us; speedup vs baseline: 1.0581x; 1.0500x over previous
//
#include <hip/hip_runtime.h>
#include <hip/hip_bf16.h>
#include <stdint.h>

#define T_TOK 8192
#define DDIM 1024
#define NEXP 8
#define IMOE 1024
#define ISH 4096
#define BK 64
#define PADTOT 17408  // 16384 pairs + 8*128 max padding

typedef __attribute__((ext_vector_type(8))) short short8;
typedef __attribute__((ext_vector_type(8))) __bf16 bf16x8;
typedef __attribute__((ext_vector_type(4))) float floatx4;

// round-to-nearest-even fp32 -> bf16 bits
__device__ __forceinline__ unsigned short f2bf(float f) {
  union { float f; unsigned u; } v; v.f = f;
  unsigned r = v.u + 0x7fffu + ((v.u >> 16) & 1u);
  return (unsigned short)(r >> 16);
}

__device__ __forceinline__ floatx4 mfma16(short8 a, short8 b, floatx4 c) {
  return __builtin_amdgcn_mfma_f32_16x16x32_bf16(
      __builtin_bit_cast(bf16x8, a), __builtin_bit_cast(bf16x8, b), c, 0, 0, 0);
}

// async global->LDS, 16B per lane; LDS base must be wave-uniform (global addr IS per-lane)
__device__ __forceinline__ void gload16(const void* g, void* l) {
  __builtin_amdgcn_global_load_lds((const __attribute__((address_space(1))) void*)g,
                                   (__attribute__((address_space(3))) void*)l, 16, 0, 0);
}

// XCD-aware bijective block swizzle (T1) + 8x8 panel grouping for L2 locality.
// Requires gm%8==0 && gn%8==0 (true for all four GEMM grids). Each XCD gets a
// contiguous wg chunk; within it, blocks walk 8m x 8n groups (~4MB working set
// = one XCD L2).
__device__ __forceinline__ void xcd_swz(int id, int gm, int gn, int& m, int& n) {
  int cpx = (gm * gn) >> 3;
  int wg = (id & 7) * cpx + (id >> 3);
  int g = wg >> 6, r = wg & 63;
  int gpr = gn >> 3;
  m = ((g / gpr) << 3) | (r >> 3);
  n = ((g % gpr) << 3) | (r & 7);
}

// XOR swizzle: LDS 16B-block b of row r holds global block (b ^ (r&7)).
// Breaks the 16-way bank-group conflict of the BK=64 row stride (128B == 32 banks).

// ---------------- conversion kernels ----------------

__global__ void k_cast(const float* __restrict__ src, unsigned short* __restrict__ dst, int n) {
  int i = (blockIdx.x * blockDim.x + threadIdx.x) * 4;
  if (i < n) {
    float4 v = *(const float4*)(src + i);
    ushort4 o;
    o.x = f2bf(v.x); o.y = f2bf(v.y); o.z = f2bf(v.z); o.w = f2bf(v.w);
    *(ushort4*)(dst + i) = o;
  }
}

// src [batch][R][C] f32 -> dst [batch][C][R] bf16  (B^T layout for GEMM)
__global__ void k_transpose_cast(const float* __restrict__ src, unsigned short* __restrict__ dst,
                                 int R, int C) {
  __shared__ float tile[32][33];
  int b = blockIdx.z;
  int c0 = blockIdx.x * 32, r0 = blockIdx.y * 32;
  const float* s = src + (size_t)b * R * C;
  unsigned short* d = dst + (size_t)b * R * C;
  int tx = threadIdx.x, ty = threadIdx.y;  // 32 x 8
#pragma unroll
  for (int j = 0; j < 32; j += 8)
    tile[ty + j][tx] = s[(size_t)(r0 + ty + j) * C + c0 + tx];
  __syncthreads();
#pragma unroll
  for (int j = 0; j < 32; j += 8)
    d[(size_t)(c0 + ty + j) * R + r0 + tx] = f2bf(tile[tx][ty + j]);
}

// ---------------- router (no global atomics) ----------------

__global__ void k_router(const float* __restrict__ x, const float* __restrict__ gw,
                         const float* __restrict__ sgw, float* __restrict__ logits_out,
                         int* __restrict__ topi, float* __restrict__ topw,
                         float* __restrict__ sgate) {
  int wave = threadIdx.x >> 6;
  int lane = threadIdx.x & 63;
  int t = blockIdx.x * 4 + wave;
  const float* xr = x + (size_t)t * DDIM;
  float acc[9];
#pragma unroll
  for (int j = 0; j < 9; j++) acc[j] = 0.f;
  for (int d = lane; d < DDIM; d += 64) {
    float xv = xr[d];
    const float* g = gw + d * 8;
    float4 g0 = *(const float4*)g;
    float4 g1 = *(const float4*)(g + 4);
    acc[0] += xv * g0.x; acc[1] += xv * g0.y; acc[2] += xv * g0.z; acc[3] += xv * g0.w;
    acc[4] += xv * g1.x; acc[5] += xv * g1.y; acc[6] += xv * g1.z; acc[7] += xv * g1.w;
    acc[8] += xv * sgw[d];
  }
#pragma unroll
  for (int off = 32; off > 0; off >>= 1) {
#pragma unroll
    for (int j = 0; j < 9; j++) acc[j] += __shfl_xor(acc[j], off);
  }
  if (lane == 0) {
#pragma unroll
    for (int j = 0; j < 8; j++) logits_out[t * 8 + j] = acc[j];
    int i0 = 0;
#pragma unroll
    for (int j = 1; j < 8; j++) if (acc[j] > acc[i0]) i0 = j;
    int i1 = -1;
#pragma unroll
    for (int j = 0; j < 8; j++) {
      if (j == i0) continue;
      if (i1 < 0 || acc[j] > acc[i1]) i1 = j;
    }
    float e1 = expf(acc[i1] - acc[i0]);  // e0 = 1
    float inv = 1.f / (1.f + e1);
    topi[t * 2] = i0; topi[t * 2 + 1] = i1;
    topw[t * 2] = inv; topw[t * 2 + 1] = e1 * inv;
    sgate[t] = 1.f / (1.f + expf(-acc[8]));
  }
}

// Counting sort pass 1: per-block expert histogram (LDS atomics only).
__global__ void k_hist(const int* __restrict__ topi, int* __restrict__ blockhist) {
  __shared__ int h[NEXP];
  if (threadIdx.x < NEXP) h[threadIdx.x] = 0;
  __syncthreads();
  int i = blockIdx.x * 256 + threadIdx.x;  // pair index
  atomicAdd(&h[topi[i]], 1);
  __syncthreads();
  if (threadIdx.x < NEXP) blockhist[blockIdx.x * NEXP + threadIdx.x] = h[threadIdx.x];
}

// Pass 2: padded segment offsets (multiples of 128) + per-block bases + real counts.
__global__ void k_offsets(const int* __restrict__ blockhist, int* __restrict__ pseg,
                          int* __restrict__ rcnt, int* __restrict__ blockbase) {
  if (threadIdx.x == 0) {
    int tot[NEXP];
#pragma unroll
    for (int e = 0; e < NEXP; e++) tot[e] = 0;
    for (int b = 0; b < 64; b++)
      for (int e = 0; e < NEXP; e++) {
        blockbase[b * NEXP + e] = tot[e];
        tot[e] += blockhist[b * NEXP + e];
      }
    int s = 0;
    for (int e = 0; e < NEXP; e++) {
      rcnt[e] = tot[e];
      pseg[e] = s;
      s += (tot[e] + 127) & ~127;  // pad each segment to 128
    }
    pseg[NEXP] = s;
    for (int b = 0; b < 64; b++)
      for (int e = 0; e < NEXP; e++) blockbase[b * NEXP + e] += pseg[e];
  }
}

// Pass 3: scatter with per-block LDS cursors (no global atomics).
__global__ void k_scatter(const int* __restrict__ topi, const float* __restrict__ topw,
                          const int* __restrict__ blockbase,
                          int* __restrict__ ptok, float* __restrict__ pw) {
  __shared__ int cur[NEXP];
  if (threadIdx.x < NEXP) cur[threadIdx.x] = blockbase[blockIdx.x * NEXP + threadIdx.x];
  __syncthreads();
  int i = blockIdx.x * 256 + threadIdx.x;  // pair index
  int e = topi[i];
  int pos = atomicAdd(&cur[e], 1);
  ptok[pos] = i >> 1;
  pw[pos] = topw[i];
}

// ---------------- GEMM kernels (MFMA bf16 16x16x32, XOR-swizzled LDS) ----------------
// 32 KB LDS/block, VGPR<=128 -> 4 blocks/CU at __launch_bounds__(256,4).
// Fused gate/up + SiLU, shared expert: C tile 128(M) x 64(N), dual-B accs.
__global__ __launch_bounds__(256, 4) void k_gu_shared(
    const unsigned short* __restrict__ Xb,   // [8192][1024]
    const unsigned short* __restrict__ BgT,  // [4096][1024]
    const unsigned short* __restrict__ BuT,  // [4096][1024]
    unsigned short* __restrict__ H)          // [8192][4096]
{
  int bm, bn;
  xcd_swz(blockIdx.x, 64, 64, bm, bn);
  const int tm0 = bm * 128;
  const int tn0 = bn * 64;

  __shared__ __align__(16) unsigned short As[128 * BK];
  __shared__ __align__(16) unsigned short Bgs[64 * BK];
  __shared__ __align__(16) unsigned short Bus[64 * BK];

  const int tid = threadIdx.x;
  const int wave = tid >> 6, lane = tid & 63;
  const int wm = wave & 1, wn = wave >> 1;
  const int quad = lane >> 4, l16 = lane & 15;
  const int srow = lane >> 3;                        // 8 lanes per 64-elem row
  const int scol = ((lane & 7) ^ srow) * 8;          // swizzled global col block

  floatx4 accg[4][2] = {};
  floatx4 accu[4][2] = {};

  for (int k0 = 0; k0 < DDIM; k0 += BK) {
#pragma unroll
    for (int s = 0; s < 4; s++) {
      int rb = (wave * 4 + s) * 8;
      gload16(Xb + (size_t)(tm0 + rb + srow) * DDIM + k0 + scol, As + rb * BK);
    }
#pragma unroll
    for (int s = 0; s < 2; s++) {
      int rb = (wave * 2 + s) * 8;
      gload16(BgT + (size_t)(tn0 + rb + srow) * DDIM + k0 + scol, Bgs + rb * BK);
      gload16(BuT + (size_t)(tn0 + rb + srow) * DDIM + k0 + scol, Bus + rb * BK);
    }
    __syncthreads();
#pragma unroll
    for (int ks = 0; ks < BK; ks += 32) {
      short8 af[4], bg[2], bu[2];
#pragma unroll
      for (int f = 0; f < 4; f++) {
        int r = wm * 64 + f * 16 + l16;
        af[f] = *(const short8*)(As + r * BK + ((((ks >> 3) + quad) ^ (r & 7)) << 3));
      }
#pragma unroll
      for (int f = 0; f < 2; f++) {
        int r = wn * 32 + f * 16 + l16;
        int off = r * BK + ((((ks >> 3) + quad) ^ (r & 7)) << 3);
        bg[f] = *(const short8*)(Bgs + off);
        bu[f] = *(const short8*)(Bus + off);
      }
#pragma unroll
      for (int fm = 0; fm < 4; fm++)
#pragma unroll
        for (int fn = 0; fn < 2; fn++) {
          accg[fm][fn] = mfma16(af[fm], bg[fn], accg[fm][fn]);
          accu[fm][fn] = mfma16(af[fm], bu[fn], accu[fm][fn]);
        }
    }
    __syncthreads();
  }
#pragma unroll
  for (int fm = 0; fm < 4; fm++)
#pragma unroll
    for (int reg = 0; reg < 4; reg++) {
      int r = tm0 + wm * 64 + fm * 16 + quad * 4 + reg;
#pragma unroll
      for (int fn = 0; fn < 2; fn++) {
        int c = tn0 + wn * 32 + fn * 16 + l16;
        float g = accg[fm][fn][reg];
        float u = accu[fm][fn][reg];
        float h = (g / (1.f + __expf(-g))) * u;
        H[(size_t)r * ISH + c] = f2bf(h);
      }
    }
}

// Fused gate/up + SiLU for routed experts — A gathered on the fly from xb via
// per-lane ptok indirection (global side of global_load_lds is per-lane).
// Pad slots read row 0 (clamped garbage ptok); their Hp rows are garbage but
// are masked at the down_expert C-write, so never observed.
__global__ __launch_bounds__(256, 4) void k_gu_expert(
    const unsigned short* __restrict__ Xb,   // [8192][1024]
    const unsigned short* __restrict__ EgT,  // [E][1024][1024]
    const unsigned short* __restrict__ EuT,
    const int* __restrict__ pseg,
    const int* __restrict__ ptok,
    unsigned short* __restrict__ Hp)         // [PADTOT][1024] by pair slot
{
  int bm, bn;
  xcd_swz(blockIdx.x, PADTOT / 128, 16, bm, bn);
  const int m0 = bm * 128;
  if (m0 >= pseg[NEXP]) return;
  int e = 0;
#pragma unroll
  for (int j = 1; j < NEXP; j++) if (m0 >= pseg[j]) e = j;

  __shared__ __align__(16) unsigned short As[128 * BK];
  __shared__ __align__(16) unsigned short Bgs[64 * BK];
  __shared__ __align__(16) unsigned short Bus[64 * BK];

  const int tn0 = bn * 64;
  const int tid = threadIdx.x;
  const int wave = tid >> 6, lane = tid & 63;
  const int wm = wave & 1, wn = wave >> 1;
  const int quad = lane >> 4, l16 = lane & 15;
  const int srow = lane >> 3;
  const int scol = ((lane & 7) ^ srow) * 8;

  const unsigned short* Bg = EgT + (size_t)e * IMOE * DDIM;
  const unsigned short* Bu = EuT + (size_t)e * IMOE * DDIM;

  // indirect A staging pointers (4 parts of 32 rows each)
  const unsigned short* ArowP[4];
#pragma unroll
  for (int s = 0; s < 4; s++) {
    int tok = ptok[m0 + (wave * 4 + s) * 8 + srow];
    if (tok < 0 || tok >= T_TOK) tok = 0;  // pad slots: ptok is garbage
    ArowP[s] = Xb + (size_t)tok * DDIM + scol;
  }

  floatx4 accg[4][2] = {};
  floatx4 accu[4][2] = {};

  for (int k0 = 0; k0 < DDIM; k0 += BK) {
#pragma unroll
    for (int s = 0; s < 4; s++) {
      int rb = (wave * 4 + s) * 8;
      gload16(ArowP[s] + k0, As + rb * BK);
    }
#pragma unroll
    for (int s = 0; s < 2; s++) {
      int rb = (wave * 2 + s) * 8;
      gload16(Bg + (size_t)(tn0 + rb + srow) * DDIM + k0 + scol, Bgs + rb * BK);
      gload16(Bu + (size_t)(tn0 + rb + srow) * DDIM + k0 + scol, Bus + rb * BK);
    }
    __syncthreads();
#pragma unroll
    for (int ks = 0; ks < BK; ks += 32) {
      short8 af[4], bg[2], bu[2];
#pragma unroll
      for (int f = 0; f < 4; f++) {
        int r = wm * 64 + f * 16 + l16;
        af[f] = *(const short8*)(As + r * BK + ((((ks >> 3) + quad) ^ (r & 7)) << 3));
      }
#pragma unroll
      for (int f = 0; f < 2; f++) {
        int r = wn * 32 + f * 16 + l16;
        int off = r * BK + ((((ks >> 3) + quad) ^ (r & 7)) << 3);
        bg[f] = *(const short8*)(Bgs + off);
        bu[f] = *(const short8*)(Bus + off);
      }
#pragma unroll
      for (int fm = 0; fm < 4; fm++)
#pragma unroll
        for (int fn = 0; fn < 2; fn++) {
          accg[fm][fn] = mfma16(af[fm], bg[fn], accg[fm][fn]);
          accu[fm][fn] = mfma16(af[fm], bu[fn], accu[fm][fn]);
        }
    }
    __syncthreads();
  }
#pragma unroll
  for (int fm = 0; fm < 4; fm++)
#pragma unroll
    for (int reg = 0; reg < 4; reg++) {
      int r = m0 + wm * 64 + fm * 16 + quad * 4 + reg;
#pragma unroll
      for (int fn = 0; fn < 2; fn++) {
        int c = tn0 + wn * 32 + fn * 16 + l16;
        float g = accg[fm][fn][reg];
        float u = accu[fm][fn][reg];
        Hp[(size_t)r * IMOE + c] = f2bf((g / (1.f + __expf(-g))) * u);
      }
    }
}

// Shared-expert down proj: out = sigmoid_gate[t] * (Hsh @ sd). Writes full out.
__global__ __launch_bounds__(256, 4) void k_down_shared(
    const unsigned short* __restrict__ Hsh,  // [8192][4096]
    const unsigned short* __restrict__ SdT,  // [1024][4096]
    const float* __restrict__ sgate,
    float* __restrict__ out)                 // [8192][1024]
{
  __shared__ __align__(16) unsigned short As[128 * BK];
  __shared__ __align__(16) unsigned short Bs[128 * BK];

  int bm, bn;
  xcd_swz(blockIdx.x, 64, 8, bm, bn);
  const int tm0 = bm * 128;
  const int tn0 = bn * 128;
  const int tid = threadIdx.x;
  const int wave = tid >> 6, lane = tid & 63;
  const int wm = wave & 1, wn = wave >> 1;
  const int quad = lane >> 4, l16 = lane & 15;
  const int srow = lane >> 3;
  const int scol = ((lane & 7) ^ srow) * 8;

  floatx4 acc[4][4] = {};

  for (int k0 = 0; k0 < ISH; k0 += BK) {
#pragma unroll
    for (int s = 0; s < 4; s++) {
      int rb = (wave * 4 + s) * 8;
      gload16(Hsh + (size_t)(tm0 + rb + srow) * ISH + k0 + scol, As + rb * BK);
      gload16(SdT + (size_t)(tn0 + rb + srow) * ISH + k0 + scol, Bs + rb * BK);
    }
    __syncthreads();
#pragma unroll
    for (int ks = 0; ks < BK; ks += 32) {
      short8 af[4], bfr[4];
#pragma unroll
      for (int f = 0; f < 4; f++) {
        int ra = wm * 64 + f * 16 + l16;
        int rb2 = wn * 64 + f * 16 + l16;
        af[f] = *(const short8*)(As + ra * BK + ((((ks >> 3) + quad) ^ (ra & 7)) << 3));
        bfr[f] = *(const short8*)(Bs + rb2 * BK + ((((ks >> 3) + quad) ^ (rb2 & 7)) << 3));
      }
#pragma unroll
      for (int fm = 0; fm < 4; fm++)
#pragma unroll
        for (int fn = 0; fn < 4; fn++)
          acc[fm][fn] = mfma16(af[fm], bfr[fn], acc[fm][fn]);
    }
    __syncthreads();
  }
#pragma unroll
  for (int fm = 0; fm < 4; fm++)
#pragma unroll
    for (int reg = 0; reg < 4; reg++) {
      int r = tm0 + wm * 64 + fm * 16 + quad * 4 + reg;
      float gt = sgate[r];
#pragma unroll
      for (int fn = 0; fn < 4; fn++) {
        int c = tn0 + wn * 64 + fn * 16 + l16;
        out[(size_t)r * DDIM + c] = gt * acc[fm][fn][reg];
      }
    }
}

// Expert down proj: out[tok] += w_pair * (Hp @ ed[e]) via atomics. Sequential A.
__global__ __launch_bounds__(256, 4) void k_down_expert(
    const unsigned short* __restrict__ Hp,   // [PADTOT][1024]
    const unsigned short* __restrict__ EdT,  // [E][1024][1024]
    const int* __restrict__ pseg,
    const int* __restrict__ rcnt,
    const int* __restrict__ ptok,
    const float* __restrict__ pw,
    float* __restrict__ out)
{
  int bm, bn;
  xcd_swz(blockIdx.x, PADTOT / 128, 8, bm, bn);
  const int m0 = bm * 128;
  if (m0 >= pseg[NEXP]) return;
  int e = 0;
#pragma unroll
  for (int j = 1; j < NEXP; j++) if (m0 >= pseg[j]) e = j;
  const int sbase = pseg[e];
  const int cnt = rcnt[e];

  __shared__ __align__(16) unsigned short As[128 * BK];
  __shared__ __align__(16) unsigned short Bs[128 * BK];

  const int tn0 = bn * 128;
  const int tid = threadIdx.x;
  const int wave = tid >> 6, lane = tid & 63;
  const int wm = wave & 1, wn = wave >> 1;
  const int quad = lane >> 4, l16 = lane & 15;
  const int srow = lane >> 3;
  const int scol = ((lane & 7) ^ srow) * 8;

  const unsigned short* B = EdT + (size_t)e * IMOE * DDIM;

  floatx4 acc[4][4] = {};

  for (int k0 = 0; k0 < IMOE; k0 += BK) {
#pragma unroll
    for (int s = 0; s < 4; s++) {
      int rb = (wave * 4 + s) * 8;
      gload16(Hp + (size_t)(m0 + rb + srow) * IMOE + k0 + scol, As + rb * BK);
      gload16(B + (size_t)(tn0 + rb + srow) * IMOE + k0 + scol, Bs + rb * BK);
    }
    __syncthreads();
#pragma unroll
    for (int ks = 0; ks < BK; ks += 32) {
      short8 af[4], bfr[4];
#pragma unroll
      for (int f = 0; f < 4; f++) {
        int ra = wm * 64 + f * 16 + l16;
        int rb2 = wn * 64 + f * 16 + l16;
        af[f] = *(const short8*)(As + ra * BK + ((((ks >> 3) + quad) ^ (ra & 7)) << 3));
        bfr[f] = *(const short8*)(Bs + rb2 * BK + ((((ks >> 3) + quad) ^ (rb2 & 7)) << 3));
      }
#pragma unroll
      for (int fm = 0; fm < 4; fm++)
#pragma unroll
        for (int fn = 0; fn < 4; fn++)
          acc[fm][fn] = mfma16(af[fm], bfr[fn], acc[fm][fn]);
    }
    __syncthreads();
  }
#pragma unroll
  for (int fm = 0; fm < 4; fm++)
#pragma unroll
    for (int reg = 0; reg < 4; reg++) {
      int grow = m0 + wm * 64 + fm * 16 + quad * 4 + reg;
      if (grow - sbase < cnt) {
        int t = ptok[grow];
        float w = pw[grow];
#pragma unroll
        for (int fn = 0; fn < 4; fn++) {
          int c = tn0 + wn * 64 + fn * 16 + l16;
          atomicAdd(&out[(size_t)t * DDIM + c], w * acc[fm][fn][reg]);
        }
      }
    }
}

// ---------------- launch ----------------

extern "C" void kernel_launch(void* const* d_in, const int* in_sizes, int n_in,
                              void* d_out, int out_size, void* d_ws, size_t ws_size,
                              hipStream_t stream) {
  const float* x   = (const float*)d_in[0];
  const float* gw  = (const float*)d_in[1];
  const float* eg  = (const float*)d_in[2];
  const float* eu  = (const float*)d_in[3];
  const float* ed  = (const float*)d_in[4];
  const float* sg  = (const float*)d_in[5];
  const float* su  = (const float*)d_in[6];
  const float* sd  = (const float*)d_in[7];
  const float* sgw = (const float*)d_in[8];

  float* out    = (float*)d_out;                 // [8192][1024]
  float* logits = out + (size_t)T_TOK * DDIM;    // [8192][8]

  char* ws = (char*)d_ws;
  unsigned short* xb   = (unsigned short*)(ws + 0);            // 16 MB
  unsigned short* egT  = (unsigned short*)(ws + 16777216);     // 16 MB
  unsigned short* euT  = (unsigned short*)(ws + 33554432);     // 16 MB
  unsigned short* edT  = (unsigned short*)(ws + 50331648);     // 16 MB
  unsigned short* sgT  = (unsigned short*)(ws + 67108864);     // 8 MB
  unsigned short* suT  = (unsigned short*)(ws + 75497472);     // 8 MB
  unsigned short* sdT  = (unsigned short*)(ws + 83886080);     // 8 MB
  unsigned short* hsh  = (unsigned short*)(ws + 92274688);     // 64 MB
  unsigned short* hp   = (unsigned short*)(ws + 159383552);    // 35.65 MB
  int*   topi      = (int*)  (ws + 195035136);   // 16384 ints
  float* topw      = (float*)(ws + 195100672);   // 16384 floats
  float* sgate     = (float*)(ws + 195166208);   // 8192 floats
  int*   ptok      = (int*)  (ws + 195198976);   // PADTOT ints
  float* pw        = (float*)(ws + 195268608);   // PADTOT floats
  int*   blockhist = (int*)  (ws + 195338240);   // 64*8 ints
  int*   blockbase = (int*)  (ws + 195340288);   // 64*8 ints
  int*   pseg      = (int*)  (ws + 195342336);   // 9 ints
  int*   rcnt      = (int*)  (ws + 195342400);   // 8 ints

  k_cast<<<8192, 256, 0, stream>>>(x, xb, T_TOK * DDIM);
  k_transpose_cast<<<dim3(32, 32, 8), dim3(32, 8), 0, stream>>>(eg, egT, DDIM, IMOE);
  k_transpose_cast<<<dim3(32, 32, 8), dim3(32, 8), 0, stream>>>(eu, euT, DDIM, IMOE);
  k_transpose_cast<<<dim3(32, 32, 8), dim3(32, 8), 0, stream>>>(ed, edT, IMOE, DDIM);
  k_transpose_cast<<<dim3(128, 32, 1), dim3(32, 8), 0, stream>>>(sg, sgT, DDIM, ISH);
  k_transpose_cast<<<dim3(128, 32, 1), dim3(32, 8), 0, stream>>>(su, suT, DDIM, ISH);
  k_transpose_cast<<<dim3(32, 128, 1), dim3(32, 8), 0, stream>>>(sd, sdT, ISH, DDIM);

  k_router<<<T_TOK / 4, 256, 0, stream>>>(x, gw, sgw, logits, topi, topw, sgate);
  k_hist<<<64, 256, 0, stream>>>(topi, blockhist);
  k_offsets<<<1, 64, 0, stream>>>(blockhist, pseg, rcnt, blockbase);
  k_scatter<<<64, 256, 0, stream>>>(topi, topw, blockbase, ptok, pw);

  k_gu_expert<<<(PADTOT / 128) * 16, 256, 0, stream>>>(xb, egT, euT, pseg, ptok, hp);
  k_gu_shared<<<64 * 64, 256, 0, stream>>>(xb, sgT, suT, hsh);
  k_down_shared<<<64 * 8, 256, 0, stream>>>(hsh, sdT, sgate, out);
  k_down_expert<<<(PADTOT / 128) * 8, 256, 0, stream>>>(hp, edT, pseg, rcnt, ptok, pw, out);

  (void)in_sizes; (void)n_in; (void)out_size; (void)ws_size;
}